// Round 4
// baseline (649.266 us; speedup 1.0000x reference)
//
#include <hip/hip_runtime.h>
#include <hip/hip_bf16.h>

typedef __attribute__((ext_vector_type(8))) short short8;
typedef __attribute__((ext_vector_type(4))) float f32x4;

#define AS1 __attribute__((address_space(1)))
#define AS3 __attribute__((address_space(3)))

static __device__ __forceinline__ short f2bf(float f) {
    __hip_bfloat16 h = __float2bfloat16(f);
    union { __hip_bfloat16 h; short s; } u;
    u.h = h;
    return u.s;
}

// ---------------- prepack kernels ----------------

__global__ __launch_bounds__(256) void prepack_w_kernel(const int* __restrict__ wq,
                                                        const float* __restrict__ scales,
                                                        short* __restrict__ Wb,
                                                        long total8) {
    long i = (long)blockIdx.x * 256 + threadIdx.x;
    if (i >= total8) return;
    const int4* p = (const int4*)wq + i * 2;
    int4 q0 = p[0], q1 = p[1];
    float s = scales[(i * 8) >> 5];
    short8 v;
    v[0] = f2bf((float)(q0.x - 128) * s);
    v[1] = f2bf((float)(q0.y - 128) * s);
    v[2] = f2bf((float)(q0.z - 128) * s);
    v[3] = f2bf((float)(q0.w - 128) * s);
    v[4] = f2bf((float)(q1.x - 128) * s);
    v[5] = f2bf((float)(q1.y - 128) * s);
    v[6] = f2bf((float)(q1.z - 128) * s);
    v[7] = f2bf((float)(q1.w - 128) * s);
    ((short8*)Wb)[i] = v;
}

__global__ __launch_bounds__(256) void prepack_x_kernel(const float* __restrict__ x,
                                                        short* __restrict__ Xb,
                                                        long total8) {
    long i = (long)blockIdx.x * 256 + threadIdx.x;
    if (i >= total8) return;
    const float4* p = (const float4*)x + i * 2;
    float4 f0 = p[0], f1 = p[1];
    short8 v;
    v[0] = f2bf(f0.x); v[1] = f2bf(f0.y); v[2] = f2bf(f0.z); v[3] = f2bf(f0.w);
    v[4] = f2bf(f1.x); v[5] = f2bf(f1.y); v[6] = f2bf(f1.z); v[7] = f2bf(f1.w);
    ((short8*)Xb)[i] = v;
}

// ---------------- 256x256 software-pipelined GEMM (prepacked bf16) ----------------
// 512 thr = 8 waves (2M x 4N), per-wave C = 128x64, BK=64, mfma 16x16x32.
// Register pipeline: phase-q head issues phase-(q+1) A ds_reads + 1 STAGE, then
// lgkmcnt(4) (all-but-newest-4) -> 16 MFMA; LDS pipe runs under the MFMA cluster.
// B frags reload once per K-tile, interleaved into q3's MFMA tail (after last use),
// reading next tile's B after a parity vmcnt+barrier at q3-head. 5 barriers/K-tile.
__global__ __launch_bounds__(512, 2)
void gemm256_kernel(const float* __restrict__ bias,
                    const short* __restrict__ Xb, const short* __restrict__ Wb,
                    float* __restrict__ out, int M, int N, int K) {
    __shared__ alignas(16) short As[4 * 8192];  // [parity*2+half][128*64]
    __shared__ alignas(16) short Bs[4 * 8192];

    const int nM = M >> 8, nN = N >> 8;
    int bid = blockIdx.x;
    {
        int nwg = nM * nN;
        if ((nwg & 7) == 0) bid = (bid & 7) * (nwg >> 3) + (bid >> 3);  // XCD swizzle
    }
    int pm, pn;
    {
        const int G = 8;
        if ((nN % G) == 0) {
            int per = nM * G;
            int grp = bid / per, in = bid % per;
            pn = grp * G + (in % G);
            pm = in / G;
        } else { pn = bid % nN; pm = bid / nN; }
    }

    const int tid  = threadIdx.x;
    const int lane = tid & 63;
    const int wid  = tid >> 6;
    const int wm   = wid >> 2;
    const int wn   = wid & 3;
    const int q4   = lane >> 4;
    const int l15  = lane & 15;
    const int lx   = lane & 7;

    const long bm = (long)pm << 8, bn = (long)pn << 8;
    const long Kl = K;
    const int  NT = K >> 6;

    int rdA[2], rdB[2];
#pragma unroll
    for (int p = 0; p < 2; ++p) {
        rdA[p] = (p * 2 + wm) * 8192 + l15 * 64;
        rdB[p] = (p * 2 + (wn >> 1)) * 8192 + ((wn & 1) * 64 + l15) * 64;
    }
    const int sg0 = (q4 ^ lx) * 8;
    const int sg1 = ((4 + q4) ^ lx) * 8;

    const int chnk    = wid * 1024;
    const int srowrel = wid * 16 + (lane >> 3);
    const int scol    = ((lane & 7) ^ (lane >> 3)) * 8;

    const short* aSrc[2][2];
    const short* bSrc[2][2];
#pragma unroll
    for (int H = 0; H < 2; ++H)
#pragma unroll
        for (int j = 0; j < 2; ++j) {
            aSrc[H][j] = Xb + (bm + H * 128 + srowrel + j * 8) * Kl + scol;
            bSrc[H][j] = Wb + (bn + H * 128 + srowrel + j * 8) * Kl + scol;
        }

#define STAGE_A(H, t1) { int p_ = (t1) & 1; long ko_ = (long)(t1) << 6;              \
    __builtin_amdgcn_global_load_lds((const AS1 void*)(aSrc[H][0] + ko_),            \
        (AS3 void*)&As[(p_ * 2 + (H)) * 8192 + chnk], 16, 0, 0);                     \
    __builtin_amdgcn_global_load_lds((const AS1 void*)(aSrc[H][1] + ko_),            \
        (AS3 void*)&As[(p_ * 2 + (H)) * 8192 + chnk + 512], 16, 0, 0); }
#define STAGE_B(H, t2) { int p_ = (t2) & 1; long ko_ = (long)(t2) << 6;              \
    __builtin_amdgcn_global_load_lds((const AS1 void*)(bSrc[H][0] + ko_),            \
        (AS3 void*)&Bs[(p_ * 2 + (H)) * 8192 + chnk], 16, 0, 0);                     \
    __builtin_amdgcn_global_load_lds((const AS1 void*)(bSrc[H][1] + ko_),            \
        (AS3 void*)&Bs[(p_ * 2 + (H)) * 8192 + chnk + 512], 16, 0, 0); }

#define LDA4(BUF, mbase, ra_) {                                                      \
    BUF[0][0] = *(const short8*)&As[(ra_) + (mbase) * 1024 + sg0];                   \
    BUF[0][1] = *(const short8*)&As[(ra_) + (mbase) * 1024 + sg1];                   \
    BUF[1][0] = *(const short8*)&As[(ra_) + ((mbase) + 1) * 1024 + sg0];             \
    BUF[1][1] = *(const short8*)&As[(ra_) + ((mbase) + 1) * 1024 + sg1]; }

#define LGKM4  asm volatile("s_waitcnt lgkmcnt(4)" ::: "memory");                    \
               __builtin_amdgcn_sched_barrier(0)
#define LGKM0  asm volatile("s_waitcnt lgkmcnt(0)" ::: "memory");                    \
               __builtin_amdgcn_sched_barrier(0)

#define MFMA_PH(row0, A) {                                                           \
    __builtin_amdgcn_s_setprio(1);                                                   \
    _Pragma("unroll")                                                                \
    for (int n = 0; n < 4; ++n)                                                      \
        acc[row0][n] = __builtin_amdgcn_mfma_f32_16x16x32_bf16(A[0][0], bfr[n][0],   \
                                                               acc[row0][n], 0,0,0); \
    _Pragma("unroll")                                                                \
    for (int n = 0; n < 4; ++n)                                                      \
        acc[row0][n] = __builtin_amdgcn_mfma_f32_16x16x32_bf16(A[0][1], bfr[n][1],   \
                                                               acc[row0][n], 0,0,0); \
    _Pragma("unroll")                                                                \
    for (int n = 0; n < 4; ++n)                                                      \
        acc[(row0)+1][n] = __builtin_amdgcn_mfma_f32_16x16x32_bf16(A[1][0],          \
                                           bfr[n][0], acc[(row0)+1][n], 0,0,0);      \
    _Pragma("unroll")                                                                \
    for (int n = 0; n < 4; ++n)                                                      \
        acc[(row0)+1][n] = __builtin_amdgcn_mfma_f32_16x16x32_bf16(A[1][1],          \
                                           bfr[n][1], acc[(row0)+1][n], 0,0,0);      \
    __builtin_amdgcn_s_setprio(0); }

    f32x4 acc[8][4];
#pragma unroll
    for (int m = 0; m < 8; ++m)
#pragma unroll
        for (int n = 0; n < 4; ++n) acc[m][n] = (f32x4){0.f, 0.f, 0.f, 0.f};

    short8 akP[2][2], akQ[2][2], bfr[4][2];

    // ---- prologue ----
    STAGE_B(0, 0); STAGE_B(1, 0); STAGE_A(0, 0); STAGE_A(1, 0);   // first 8
    STAGE_B(0, 1); STAGE_B(1, 1);                                 // +4 (NT>=2)
    asm volatile("s_waitcnt vmcnt(4)" ::: "memory");              // tile-0 resident
    __builtin_amdgcn_s_barrier();
    LDA4(akP, 0, rdA[0]);                                         // A(0) m{0,1}
#pragma unroll
    for (int n = 0; n < 4; ++n) {
        bfr[n][0] = *(const short8*)&Bs[rdB[0] + n * 1024 + sg0];
        bfr[n][1] = *(const short8*)&Bs[rdB[0] + n * 1024 + sg1];
    }

    for (int t = 0; t < NT - 1; ++t) {
        const int par = t & 1;
        const int ra = rdA[par], ran = rdA[par ^ 1], rbn = rdB[par ^ 1];
        const bool s2 = (t + 2 < NT);

        // ---- q0 ----
        LDA4(akQ, 2, ra);
        STAGE_A(0, t + 1);
        LGKM4;                       // akP + bfr ready; akQ in flight
        MFMA_PH(0, akP);
        __builtin_amdgcn_s_barrier();
        // ---- q1 ----
        LDA4(akP, 4, ra);
        STAGE_A(1, t + 1);
        LGKM4;
        MFMA_PH(2, akQ);
        __builtin_amdgcn_s_barrier();
        // ---- q2 ----
        LDA4(akQ, 6, ra);
        if (s2) STAGE_B(0, t + 2);
        LGKM4;
        MFMA_PH(4, akP);
        __builtin_amdgcn_s_barrier();
        // ---- q3: parity transition + B reload interleaved into MFMA tail ----
        if (s2) { asm volatile("s_waitcnt vmcnt(2)" ::: "memory"); }
        else    { asm volatile("s_waitcnt vmcnt(0)" ::: "memory"); }
        __builtin_amdgcn_s_barrier();       // parity: A(t+1),B(t+1) visible
        LDA4(akP, 0, ran);                  // A(t+1) m{0,1}
        if (s2) STAGE_B(1, t + 2);
        LGKM4;                              // akQ(m67) ready; akP(next) in flight
        __builtin_amdgcn_s_setprio(1);
#pragma unroll
        for (int n = 0; n < 4; ++n)
            acc[6][n] = __builtin_amdgcn_mfma_f32_16x16x32_bf16(akQ[0][0], bfr[n][0],
                                                                acc[6][n], 0, 0, 0);
#pragma unroll
        for (int n = 0; n < 4; ++n)
            acc[6][n] = __builtin_amdgcn_mfma_f32_16x16x32_bf16(akQ[0][1], bfr[n][1],
                                                                acc[6][n], 0, 0, 0);
#pragma unroll
        for (int n = 0; n < 4; ++n) {       // last use of bfr[n][0] -> reload B(t+1)
            acc[7][n] = __builtin_amdgcn_mfma_f32_16x16x32_bf16(akQ[1][0], bfr[n][0],
                                                                acc[7][n], 0, 0, 0);
            bfr[n][0] = *(const short8*)&Bs[rbn + n * 1024 + sg0];
        }
#pragma unroll
        for (int n = 0; n < 4; ++n) {       // last use of bfr[n][1] -> reload
            acc[7][n] = __builtin_amdgcn_mfma_f32_16x16x32_bf16(akQ[1][1], bfr[n][1],
                                                                acc[7][n], 0, 0, 0);
            bfr[n][1] = *(const short8*)&Bs[rbn + n * 1024 + sg1];
        }
        __builtin_amdgcn_s_setprio(0);
        __builtin_amdgcn_s_barrier();       // group trailing
    }

    // ---- final group (t = NT-1): no staging, no parity transition ----
    {
        const int ra = rdA[(NT - 1) & 1];
        LDA4(akQ, 2, ra);
        LGKM4;
        MFMA_PH(0, akP);
        __builtin_amdgcn_s_barrier();
        LDA4(akP, 4, ra);
        LGKM4;
        MFMA_PH(2, akQ);
        __builtin_amdgcn_s_barrier();
        LDA4(akQ, 6, ra);
        LGKM4;
        MFMA_PH(4, akP);
        LGKM0;
        MFMA_PH(6, akQ);
    }

    // ---- epilogue: C/D layout col = lane&15, row = (lane>>4)*4 + reg ----
#pragma unroll
    for (int n = 0; n < 4; ++n) {
        long col = bn + wn * 64 + n * 16 + l15;
        float bv = bias[col];
#pragma unroll
        for (int m = 0; m < 8; ++m) {
            long row = bm + wm * 128 + m * 16 + q4 * 4;
#pragma unroll
            for (int r = 0; r < 4; ++r)
                out[(row + r) * (long)N + col] = acc[m][n][r] + bv;
        }
    }
#undef STAGE_A
#undef STAGE_B
#undef LDA4
#undef LGKM4
#undef LGKM0
#undef MFMA_PH
}

// ---------------- fallback 128x128 GEMM (handles fused / odd shapes) ----------------

template <bool PRE_A, bool PRE_B>
__global__ __launch_bounds__(256, 2)
void gemm_kernel(const float* __restrict__ x, const int* __restrict__ wq,
                 const float* __restrict__ scales, const float* __restrict__ bias,
                 const short* __restrict__ Xb, const short* __restrict__ Wb,
                 float* __restrict__ out, int M, int N, int K) {
    constexpr int BM = 128, BN = 128, BK = 64;
    __shared__ alignas(16) short As[BM * BK];
    __shared__ alignas(16) short Bs[BN * BK];

    const int nM = M / BM, nN = N / BN;
    int bid = blockIdx.x;
    int pm, pn;
    const int G = 8;
    if ((nN % G) == 0) {
        int per = nM * G;
        int grp = bid / per;
        int in  = bid % per;
        pn = grp * G + (in % G);
        pm = in / G;
    } else {
        pn = bid % nN;
        pm = bid / nN;
    }

    const int tid  = threadIdx.x;
    const int lane = tid & 63;
    const int wv   = tid >> 6;
    const int wm   = (wv >> 1) * 64;
    const int wn   = (wv & 1) * 64;
    const int q    = lane >> 4;
    const int l15  = lane & 15;
    const int sxor = lane & 7;

    const long bm = (long)pm * BM, bn = (long)pn * BN;

    f32x4 acc[4][4];
#pragma unroll
    for (int i = 0; i < 4; ++i)
#pragma unroll
        for (int j = 0; j < 4; ++j) acc[i][j] = (f32x4){0.f, 0.f, 0.f, 0.f};

    const int srow = tid >> 3;
    const int scg  = tid & 7;

    const int sg0   = q ^ sxor;
    const int aOff0 = (wm + l15) * 64 + sg0 * 8;
    const int aOff1 = (wm + l15) * 64 + (sg0 ^ 4) * 8;
    const int bOff0 = (wn + l15) * 64 + sg0 * 8;
    const int bOff1 = (wn + l15) * 64 + (sg0 ^ 4) * 8;

    const int prRow  = lane >> 3;
    const int prGsrc = (lane & 7) ^ (lane >> 3);

    for (int k0 = 0; k0 < K; k0 += BK) {
        if constexpr (PRE_A) {
#pragma unroll
            for (int i = 0; i < 4; ++i) {
                int r = wv * 32 + i * 8 + prRow;
                const short* src = Xb + (bm + r) * (long)K + k0 + prGsrc * 8;
                __builtin_amdgcn_global_load_lds((const AS1 void*)src,
                                                 (AS3 void*)&As[(wv * 32 + i * 8) * 64],
                                                 16, 0, 0);
            }
        } else {
#pragma unroll
            for (int i = 0; i < 4; ++i) {
                int r = i * 32 + srow;
                const float4* p = (const float4*)(x + (bm + r) * (long)K + k0 + scg * 8);
                float4 f0 = p[0], f1 = p[1];
                short8 v;
                v[0] = f2bf(f0.x); v[1] = f2bf(f0.y); v[2] = f2bf(f0.z); v[3] = f2bf(f0.w);
                v[4] = f2bf(f1.x); v[5] = f2bf(f1.y); v[6] = f2bf(f1.z); v[7] = f2bf(f1.w);
                int sg = scg ^ (r & 7);
                *(short8*)&As[r * 64 + sg * 8] = v;
            }
        }
        if constexpr (PRE_B) {
#pragma unroll
            for (int i = 0; i < 4; ++i) {
                int r = wv * 32 + i * 8 + prRow;
                const short* src = Wb + (bn + r) * (long)K + k0 + prGsrc * 8;
                __builtin_amdgcn_global_load_lds((const AS1 void*)src,
                                                 (AS3 void*)&Bs[(wv * 32 + i * 8) * 64],
                                                 16, 0, 0);
            }
        } else {
#pragma unroll
            for (int i = 0; i < 4; ++i) {
                int r = i * 32 + srow;
                const int4* p = (const int4*)(wq + (bn + r) * (long)K + k0 + scg * 8);
                int4 q0 = p[0], q1 = p[1];
                float s = scales[(bn + r) * (long)(K >> 5) + ((k0 + scg * 8) >> 5)];
                short8 v;
                v[0] = f2bf((float)(q0.x - 128) * s);
                v[1] = f2bf((float)(q0.y - 128) * s);
                v[2] = f2bf((float)(q0.z - 128) * s);
                v[3] = f2bf((float)(q0.w - 128) * s);
                v[4] = f2bf((float)(q1.x - 128) * s);
                v[5] = f2bf((float)(q1.y - 128) * s);
                v[6] = f2bf((float)(q1.z - 128) * s);
                v[7] = f2bf((float)(q1.w - 128) * s);
                int sg = scg ^ (r & 7);
                *(short8*)&Bs[r * 64 + sg * 8] = v;
            }
        }
        __syncthreads();

#pragma unroll
        for (int kk = 0; kk < 2; ++kk) {
            short8 a[4], b[4];
            const int aBase = kk ? aOff1 : aOff0;
            const int bBase = kk ? bOff1 : bOff0;
#pragma unroll
            for (int mi = 0; mi < 4; ++mi) a[mi] = *(const short8*)&As[aBase + mi * 16 * 64];
#pragma unroll
            for (int nj = 0; nj < 4; ++nj) b[nj] = *(const short8*)&Bs[bBase + nj * 16 * 64];
#pragma unroll
            for (int mi = 0; mi < 4; ++mi)
#pragma unroll
                for (int nj = 0; nj < 4; ++nj)
                    acc[mi][nj] = __builtin_amdgcn_mfma_f32_16x16x32_bf16(
                        a[mi], b[nj], acc[mi][nj], 0, 0, 0);
        }
        __syncthreads();
    }

#pragma unroll
    for (int nj = 0; nj < 4; ++nj) {
        long col = bn + wn + nj * 16 + l15;
        float bv = bias[col];
#pragma unroll
        for (int mi = 0; mi < 4; ++mi) {
            long row = bm + wm + mi * 16 + q * 4;
#pragma unroll
            for (int r2 = 0; r2 < 4; ++r2)
                out[(row + r2) * (long)N + col] = acc[mi][nj][r2] + bv;
        }
    }
}

// ---------------- launch ----------------

extern "C" void kernel_launch(void* const* d_in, const int* in_sizes, int n_in,
                              void* d_out, int out_size, void* d_ws, size_t ws_size,
                              hipStream_t stream) {
    const float* x      = (const float*)d_in[0];
    const int*   wq     = (const int*)d_in[1];
    const float* scales = (const float*)d_in[2];
    const float* bias   = (const float*)d_in[3];
    float*       out    = (float*)d_out;

    const long N = (long)in_sizes[3];
    const long K = (long)in_sizes[1] / N;
    const long M = (long)in_sizes[0] / K;

    const size_t needW = (size_t)N * K * sizeof(short);
    const size_t needX = (size_t)M * K * sizeof(short);

    short* Wb = (short*)d_ws;
    short* Xb = Wb + (size_t)N * K;

    const bool preB = (d_ws != nullptr) && ws_size >= needW;
    const bool preA = preB && ws_size >= (needW + needX);

    if (preB) {
        long t8 = N * K / 8;
        prepack_w_kernel<<<dim3((unsigned)((t8 + 255) / 256)), dim3(256), 0, stream>>>(
            wq, scales, Wb, t8);
    }
    if (preA) {
        long t8 = M * K / 8;
        prepack_x_kernel<<<dim3((unsigned)((t8 + 255) / 256)), dim3(256), 0, stream>>>(
            x, Xb, t8);
    }

    const bool big = preA && (M % 256 == 0) && (N % 256 == 0) && (K % 64 == 0) && (K / 64 >= 2);

    if (big) {
        dim3 grid((unsigned)((M / 256) * (N / 256))), block(512);
        gemm256_kernel<<<grid, block, 0, stream>>>(bias, Xb, Wb, out, (int)M, (int)N, (int)K);
    } else {
        dim3 grid((unsigned)((M / 128) * (N / 128))), block(256);
        if (preA)
            gemm_kernel<true, true><<<grid, block, 0, stream>>>(x, wq, scales, bias, Xb, Wb,
                                                                out, (int)M, (int)N, (int)K);
        else if (preB)
            gemm_kernel<false, true><<<grid, block, 0, stream>>>(x, wq, scales, bias, Xb, Wb,
                                                                 out, (int)M, (int)N, (int)K);
        else
            gemm_kernel<false, false><<<grid, block, 0, stream>>>(x, wq, scales, bias, Xb, Wb,
                                                                  out, (int)M, (int)N, (int)K);
    }
}

// Round 5
// 605.476 us; speedup vs baseline: 1.0723x; 1.0723x over previous
//
#include <hip/hip_runtime.h>
#include <hip/hip_bf16.h>

typedef __attribute__((ext_vector_type(8))) short short8;
typedef __attribute__((ext_vector_type(4))) float f32x4;

#define AS1 __attribute__((address_space(1)))
#define AS3 __attribute__((address_space(3)))

static __device__ __forceinline__ short f2bf(float f) {
    __hip_bfloat16 h = __float2bfloat16(f);
    union { __hip_bfloat16 h; short s; } u;
    u.h = h;
    return u.s;
}

// ---------------- prepack kernels ----------------

__global__ __launch_bounds__(256) void prepack_w_kernel(const int* __restrict__ wq,
                                                        const float* __restrict__ scales,
                                                        short* __restrict__ Wb,
                                                        long total8) {
    long i = (long)blockIdx.x * 256 + threadIdx.x;
    if (i >= total8) return;
    const int4* p = (const int4*)wq + i * 2;
    int4 q0 = p[0], q1 = p[1];
    float s = scales[(i * 8) >> 5];
    short8 v;
    v[0] = f2bf((float)(q0.x - 128) * s);
    v[1] = f2bf((float)(q0.y - 128) * s);
    v[2] = f2bf((float)(q0.z - 128) * s);
    v[3] = f2bf((float)(q0.w - 128) * s);
    v[4] = f2bf((float)(q1.x - 128) * s);
    v[5] = f2bf((float)(q1.y - 128) * s);
    v[6] = f2bf((float)(q1.z - 128) * s);
    v[7] = f2bf((float)(q1.w - 128) * s);
    ((short8*)Wb)[i] = v;
}

__global__ __launch_bounds__(256) void prepack_x_kernel(const float* __restrict__ x,
                                                        short* __restrict__ Xb,
                                                        long total8) {
    long i = (long)blockIdx.x * 256 + threadIdx.x;
    if (i >= total8) return;
    const float4* p = (const float4*)x + i * 2;
    float4 f0 = p[0], f1 = p[1];
    short8 v;
    v[0] = f2bf(f0.x); v[1] = f2bf(f0.y); v[2] = f2bf(f0.z); v[3] = f2bf(f0.w);
    v[4] = f2bf(f1.x); v[5] = f2bf(f1.y); v[6] = f2bf(f1.z); v[7] = f2bf(f1.w);
    ((short8*)Xb)[i] = v;
}

// ---------------- 256x256 8-phase GEMM, 2 K-tiles/iteration, compile-time parity ----
// 512 thr = 8 waves (2M x 4N), per-wave C = 128x64, BK=64, mfma 16x16x32.
// LDS slots: A/B each [par*2+half][128 rows x 64 bf16]; granule(16B) XOR swizzle.
// Iteration (tiles t par0, t+1 par1), phase = {QUAD reads (+B burst @quad0, lgkm(8)),
// stage 1 half-tile, barrier, lgkm(0)+schedbar, setprio(1) 16 MFMA setprio(0),
// [vmcnt(4) @ph3/ph7], barrier}.
// Stage map (race-free, ledger-closed):
//   ph0: A0(t+1)->par1   ph1: A1(t+1)->par1   (par1-A freed at prev ph7 barrier)
//   ph2: B0(t+2)->par0   ph3: B1(t+2)->par0   (par0-B freed at ph0 barrier)
//   ph4: A0(t+2)->par0   ph5: A1(t+2)->par0   (par0-A freed at ph3 barrier)
//   ph6: B0(t+3)->par1   ph7: B1(t+3)->par1   (par1-B freed at ph4 barrier)
// vmcnt(4)@ph3: outstanding B(t+1)4+A(t+1)4+B(t+2)4=12 -> lands B(t+1),A(t+1).
// vmcnt(4)@ph7: outstanding B(t+2)4+A(t+2)4+B(t+3)4=12 -> lands B(t+2),A(t+2).
__global__ __launch_bounds__(512, 2)
void gemm256_kernel(const float* __restrict__ bias,
                    const short* __restrict__ Xb, const short* __restrict__ Wb,
                    float* __restrict__ out, int M, int N, int K) {
    __shared__ alignas(16) short As[4 * 8192];
    __shared__ alignas(16) short Bs[4 * 8192];

    const int nM = M >> 8, nN = N >> 8;
    int bid = blockIdx.x;
    {
        int nwg = nM * nN;
        if ((nwg & 7) == 0) bid = (bid & 7) * (nwg >> 3) + (bid >> 3);  // XCD swizzle
    }
    int pm, pn;
    {
        const int G = 8;
        if ((nN % G) == 0) {
            int per = nM * G;
            int grp = bid / per, in = bid % per;
            pn = grp * G + (in % G);
            pm = in / G;
        } else { pn = bid % nN; pm = bid / nN; }
    }

    const int tid  = threadIdx.x;
    const int lane = tid & 63;
    const int wid  = tid >> 6;
    const int wm   = wid >> 2;
    const int wn   = wid & 3;
    const int q4   = lane >> 4;
    const int l15  = lane & 15;
    const int lx   = lane & 7;

    const long bm = (long)pm << 8, bn = (long)pn << 8;
    const long Kl = K;
    const int  NT = K >> 6;

    // loop-invariant LDS read bases (shorts); parity compile-time per phase
    const int rA0 = wm * 8192 + l15 * 64;
    const int rA1 = (2 + wm) * 8192 + l15 * 64;
    const int rB0 = (wn >> 1) * 8192 + ((wn & 1) * 64 + l15) * 64;
    const int rB1 = (2 + (wn >> 1)) * 8192 + ((wn & 1) * 64 + l15) * 64;
    const int sg0 = (q4 ^ lx) * 8;
    const int sg1 = ((4 + q4) ^ lx) * 8;

    // staging geometry
    const int chnk    = wid * 1024;
    const int srowrel = wid * 16 + (lane >> 3);
    const int scol    = ((lane & 7) ^ (lane >> 3)) * 8;

    const short* aS00 = Xb + (bm + 0   + srowrel + 0) * Kl + scol;
    const short* aS01 = Xb + (bm + 0   + srowrel + 8) * Kl + scol;
    const short* aS10 = Xb + (bm + 128 + srowrel + 0) * Kl + scol;
    const short* aS11 = Xb + (bm + 128 + srowrel + 8) * Kl + scol;
    const short* bS00 = Wb + (bn + 0   + srowrel + 0) * Kl + scol;
    const short* bS01 = Wb + (bn + 0   + srowrel + 8) * Kl + scol;
    const short* bS10 = Wb + (bn + 128 + srowrel + 0) * Kl + scol;
    const short* bS11 = Wb + (bn + 128 + srowrel + 8) * Kl + scol;

#define STGA(H, PARL, OFF) {                                                          \
    __builtin_amdgcn_global_load_lds((const AS1 void*)(aS##H##0 + (OFF)),             \
        (AS3 void*)&As[((PARL) * 2 + (H)) * 8192 + chnk], 16, 0, 0);                  \
    __builtin_amdgcn_global_load_lds((const AS1 void*)(aS##H##1 + (OFF)),             \
        (AS3 void*)&As[((PARL) * 2 + (H)) * 8192 + chnk + 512], 16, 0, 0); }
#define STGB(H, PARL, OFF) {                                                          \
    __builtin_amdgcn_global_load_lds((const AS1 void*)(bS##H##0 + (OFF)),             \
        (AS3 void*)&Bs[((PARL) * 2 + (H)) * 8192 + chnk], 16, 0, 0);                  \
    __builtin_amdgcn_global_load_lds((const AS1 void*)(bS##H##1 + (OFF)),             \
        (AS3 void*)&Bs[((PARL) * 2 + (H)) * 8192 + chnk + 512], 16, 0, 0); }

#define QUAD(Q, RA) {                                                                 \
    ak[0][0] = *(const short8*)&As[(RA) + (2 * (Q)) * 1024 + sg0];                    \
    ak[0][1] = *(const short8*)&As[(RA) + (2 * (Q)) * 1024 + sg1];                    \
    ak[1][0] = *(const short8*)&As[(RA) + (2 * (Q) + 1) * 1024 + sg0];                \
    ak[1][1] = *(const short8*)&As[(RA) + (2 * (Q) + 1) * 1024 + sg1]; }
#define LDB8(RB) { _Pragma("unroll") for (int n = 0; n < 4; ++n) {                    \
    bfr[n][0] = *(const short8*)&Bs[(RB) + n * 1024 + sg0];                           \
    bfr[n][1] = *(const short8*)&Bs[(RB) + n * 1024 + sg1]; } }

#define MFMA16(Q) { __builtin_amdgcn_s_setprio(1);                                    \
    _Pragma("unroll") for (int mi = 0; mi < 2; ++mi) {                                \
        _Pragma("unroll") for (int n = 0; n < 4; ++n)                                 \
            acc[2 * (Q) + mi][n] = __builtin_amdgcn_mfma_f32_16x16x32_bf16(           \
                ak[mi][0], bfr[n][0], acc[2 * (Q) + mi][n], 0, 0, 0);                 \
        _Pragma("unroll") for (int n = 0; n < 4; ++n)                                 \
            acc[2 * (Q) + mi][n] = __builtin_amdgcn_mfma_f32_16x16x32_bf16(           \
                ak[mi][1], bfr[n][1], acc[2 * (Q) + mi][n], 0, 0, 0); }               \
    __builtin_amdgcn_s_setprio(0); }

#define BAR  __builtin_amdgcn_s_barrier()
#define WLG0 { asm volatile("s_waitcnt lgkmcnt(0)" ::: "memory");                     \
               __builtin_amdgcn_sched_barrier(0); }
#define WLG8 asm volatile("s_waitcnt lgkmcnt(8)" ::: "memory")

    f32x4 acc[8][4];
#pragma unroll
    for (int m = 0; m < 8; ++m)
#pragma unroll
        for (int n = 0; n < 4; ++n) acc[m][n] = (f32x4){0.f, 0.f, 0.f, 0.f};

    short8 ak[2][2], bfr[4][2];

    // ---- prologue: B(0),A(0) par0; B(1) par1; keep B(1) in flight ----
    STGB(0, 0, 0); STGB(1, 0, 0);
    STGA(0, 0, 0); STGA(1, 0, 0);
    STGB(0, 1, 64); STGB(1, 1, 64);
    asm volatile("s_waitcnt vmcnt(4)" ::: "memory");
    BAR;

    // ---- main loop: iterations with full staging (t, t+1), t+3 < NT ----
    for (int t = 0; t + 3 < NT; t += 2) {
        const long o1 = ((long)t + 1) << 6;
        const long o2 = o1 + 64;
        const long o3 = o2 + 64;
        // ph0
        QUAD(0, rA0); LDB8(rB0); STGA(0, 1, o1); WLG8; BAR; WLG0; MFMA16(0); BAR;
        // ph1
        QUAD(1, rA0); STGA(1, 1, o1); BAR; WLG0; MFMA16(1); BAR;
        // ph2
        QUAD(2, rA0); STGB(0, 0, o2); BAR; WLG0; MFMA16(2); BAR;
        // ph3
        QUAD(3, rA0); STGB(1, 0, o2); BAR; WLG0; MFMA16(3);
        asm volatile("s_waitcnt vmcnt(4)" ::: "memory"); BAR;
        // ph4
        QUAD(0, rA1); LDB8(rB1); STGA(0, 0, o2); WLG8; BAR; WLG0; MFMA16(0); BAR;
        // ph5
        QUAD(1, rA1); STGA(1, 0, o2); BAR; WLG0; MFMA16(1); BAR;
        // ph6
        QUAD(2, rA1); STGB(0, 1, o3); BAR; WLG0; MFMA16(2); BAR;
        // ph7
        QUAD(3, rA1); STGB(1, 1, o3); BAR; WLG0; MFMA16(3);
        asm volatile("s_waitcnt vmcnt(4)" ::: "memory"); BAR;
    }

    // ---- final iteration (t = NT-2): stage only A(NT-1); drain at ph3 ----
    {
        const long o1 = ((long)NT - 1) << 6;
        // ph0
        QUAD(0, rA0); LDB8(rB0); STGA(0, 1, o1); WLG8; BAR; WLG0; MFMA16(0); BAR;
        // ph1
        QUAD(1, rA0); STGA(1, 1, o1); BAR; WLG0; MFMA16(1); BAR;
        // ph2
        QUAD(2, rA0); BAR; WLG0; MFMA16(2); BAR;
        // ph3
        QUAD(3, rA0); BAR; WLG0; MFMA16(3);
        asm volatile("s_waitcnt vmcnt(0)" ::: "memory"); BAR;
        // ph4
        QUAD(0, rA1); LDB8(rB1); WLG8; BAR; WLG0; MFMA16(0); BAR;
        // ph5
        QUAD(1, rA1); BAR; WLG0; MFMA16(1); BAR;
        // ph6
        QUAD(2, rA1); BAR; WLG0; MFMA16(2); BAR;
        // ph7
        QUAD(3, rA1); WLG0; MFMA16(3);
    }

    // ---- epilogue: C/D layout col = lane&15, row = (lane>>4)*4 + reg ----
#pragma unroll
    for (int n = 0; n < 4; ++n) {
        long col = bn + wn * 64 + n * 16 + l15;
        float bv = bias[col];
#pragma unroll
        for (int m = 0; m < 8; ++m) {
            long row = bm + wm * 128 + m * 16 + q4 * 4;
#pragma unroll
            for (int r = 0; r < 4; ++r)
                out[(row + r) * (long)N + col] = acc[m][n][r] + bv;
        }
    }
#undef STGA
#undef STGB
#undef QUAD
#undef LDB8
#undef MFMA16
#undef BAR
#undef WLG0
#undef WLG8
}

// ---------------- fallback 128x128 GEMM (handles fused / odd shapes) ----------------

template <bool PRE_A, bool PRE_B>
__global__ __launch_bounds__(256, 2)
void gemm_kernel(const float* __restrict__ x, const int* __restrict__ wq,
                 const float* __restrict__ scales, const float* __restrict__ bias,
                 const short* __restrict__ Xb, const short* __restrict__ Wb,
                 float* __restrict__ out, int M, int N, int K) {
    constexpr int BM = 128, BN = 128, BK = 64;
    __shared__ alignas(16) short As[BM * BK];
    __shared__ alignas(16) short Bs[BN * BK];

    const int nM = M / BM, nN = N / BN;
    int bid = blockIdx.x;
    int pm, pn;
    const int G = 8;
    if ((nN % G) == 0) {
        int per = nM * G;
        int grp = bid / per;
        int in  = bid % per;
        pn = grp * G + (in % G);
        pm = in / G;
    } else {
        pn = bid % nN;
        pm = bid / nN;
    }

    const int tid  = threadIdx.x;
    const int lane = tid & 63;
    const int wv   = tid >> 6;
    const int wm   = (wv >> 1) * 64;
    const int wn   = (wv & 1) * 64;
    const int q    = lane >> 4;
    const int l15  = lane & 15;
    const int sxor = lane & 7;

    const long bm = (long)pm * BM, bn = (long)pn * BN;

    f32x4 acc[4][4];
#pragma unroll
    for (int i = 0; i < 4; ++i)
#pragma unroll
        for (int j = 0; j < 4; ++j) acc[i][j] = (f32x4){0.f, 0.f, 0.f, 0.f};

    const int srow = tid >> 3;
    const int scg  = tid & 7;

    const int sg0   = q ^ sxor;
    const int aOff0 = (wm + l15) * 64 + sg0 * 8;
    const int aOff1 = (wm + l15) * 64 + (sg0 ^ 4) * 8;
    const int bOff0 = (wn + l15) * 64 + sg0 * 8;
    const int bOff1 = (wn + l15) * 64 + (sg0 ^ 4) * 8;

    const int prRow  = lane >> 3;
    const int prGsrc = (lane & 7) ^ (lane >> 3);

    for (int k0 = 0; k0 < K; k0 += BK) {
        if constexpr (PRE_A) {
#pragma unroll
            for (int i = 0; i < 4; ++i) {
                int r = wv * 32 + i * 8 + prRow;
                const short* src = Xb + (bm + r) * (long)K + k0 + prGsrc * 8;
                __builtin_amdgcn_global_load_lds((const AS1 void*)src,
                                                 (AS3 void*)&As[(wv * 32 + i * 8) * 64],
                                                 16, 0, 0);
            }
        } else {
#pragma unroll
            for (int i = 0; i < 4; ++i) {
                int r = i * 32 + srow;
                const float4* p = (const float4*)(x + (bm + r) * (long)K + k0 + scg * 8);
                float4 f0 = p[0], f1 = p[1];
                short8 v;
                v[0] = f2bf(f0.x); v[1] = f2bf(f0.y); v[2] = f2bf(f0.z); v[3] = f2bf(f0.w);
                v[4] = f2bf(f1.x); v[5] = f2bf(f1.y); v[6] = f2bf(f1.z); v[7] = f2bf(f1.w);
                int sg = scg ^ (r & 7);
                *(short8*)&As[r * 64 + sg * 8] = v;
            }
        }
        if constexpr (PRE_B) {
#pragma unroll
            for (int i = 0; i < 4; ++i) {
                int r = wv * 32 + i * 8 + prRow;
                const short* src = Wb + (bn + r) * (long)K + k0 + prGsrc * 8;
                __builtin_amdgcn_global_load_lds((const AS1 void*)src,
                                                 (AS3 void*)&Bs[(wv * 32 + i * 8) * 64],
                                                 16, 0, 0);
            }
        } else {
#pragma unroll
            for (int i = 0; i < 4; ++i) {
                int r = i * 32 + srow;
                const int4* p = (const int4*)(wq + (bn + r) * (long)K + k0 + scg * 8);
                int4 q0 = p[0], q1 = p[1];
                float s = scales[(bn + r) * (long)(K >> 5) + ((k0 + scg * 8) >> 5)];
                short8 v;
                v[0] = f2bf((float)(q0.x - 128) * s);
                v[1] = f2bf((float)(q0.y - 128) * s);
                v[2] = f2bf((float)(q0.z - 128) * s);
                v[3] = f2bf((float)(q0.w - 128) * s);
                v[4] = f2bf((float)(q1.x - 128) * s);
                v[5] = f2bf((float)(q1.y - 128) * s);
                v[6] = f2bf((float)(q1.z - 128) * s);
                v[7] = f2bf((float)(q1.w - 128) * s);
                int sg = scg ^ (r & 7);
                *(short8*)&Bs[r * 64 + sg * 8] = v;
            }
        }
        __syncthreads();

#pragma unroll
        for (int kk = 0; kk < 2; ++kk) {
            short8 a[4], b[4];
            const int aBase = kk ? aOff1 : aOff0;
            const int bBase = kk ? bOff1 : bOff0;
#pragma unroll
            for (int mi = 0; mi < 4; ++mi) a[mi] = *(const short8*)&As[aBase + mi * 16 * 64];
#pragma unroll
            for (int nj = 0; nj < 4; ++nj) b[nj] = *(const short8*)&Bs[bBase + nj * 16 * 64];
#pragma unroll
            for (int mi = 0; mi < 4; ++mi)
#pragma unroll
                for (int nj = 0; nj < 4; ++nj)
                    acc[mi][nj] = __builtin_amdgcn_mfma_f32_16x16x32_bf16(
                        a[mi], b[nj], acc[mi][nj], 0, 0, 0);
        }
        __syncthreads();
    }

#pragma unroll
    for (int nj = 0; nj < 4; ++nj) {
        long col = bn + wn + nj * 16 + l15;
        float bv = bias[col];
#pragma unroll
        for (int mi = 0; mi < 4; ++mi) {
            long row = bm + wm + mi * 16 + q * 4;
#pragma unroll
            for (int r2 = 0; r2 < 4; ++r2)
                out[(row + r2) * (long)N + col] = acc[mi][nj][r2] + bv;
        }
    }
}

// ---------------- launch ----------------

extern "C" void kernel_launch(void* const* d_in, const int* in_sizes, int n_in,
                              void* d_out, int out_size, void* d_ws, size_t ws_size,
                              hipStream_t stream) {
    const float* x      = (const float*)d_in[0];
    const int*   wq     = (const int*)d_in[1];
    const float* scales = (const float*)d_in[2];
    const float* bias   = (const float*)d_in[3];
    float*       out    = (float*)d_out;

    const long N = (long)in_sizes[3];
    const long K = (long)in_sizes[1] / N;
    const long M = (long)in_sizes[0] / K;

    const size_t needW = (size_t)N * K * sizeof(short);
    const size_t needX = (size_t)M * K * sizeof(short);

    short* Wb = (short*)d_ws;
    short* Xb = Wb + (size_t)N * K;

    const bool preB = (d_ws != nullptr) && ws_size >= needW;
    const bool preA = preB && ws_size >= (needW + needX);

    if (preB) {
        long t8 = N * K / 8;
        prepack_w_kernel<<<dim3((unsigned)((t8 + 255) / 256)), dim3(256), 0, stream>>>(
            wq, scales, Wb, t8);
    }
    if (preA) {
        long t8 = M * K / 8;
        prepack_x_kernel<<<dim3((unsigned)((t8 + 255) / 256)), dim3(256), 0, stream>>>(
            x, Xb, t8);
    }

    const long NTl = K / 64;
    const bool big = preA && (M % 256 == 0) && (N % 256 == 0) && (K % 64 == 0) &&
                     (NTl >= 2) && (NTl % 2 == 0);

    if (big) {
        dim3 grid((unsigned)((M / 256) * (N / 256))), block(512);
        gemm256_kernel<<<grid, block, 0, stream>>>(bias, Xb, Wb, out, (int)M, (int)N, (int)K);
    } else {
        dim3 grid((unsigned)((M / 128) * (N / 128))), block(256);
        if (preA)
            gemm_kernel<true, true><<<grid, block, 0, stream>>>(x, wq, scales, bias, Xb, Wb,
                                                                out, (int)M, (int)N, (int)K);
        else if (preB)
            gemm_kernel<false, true><<<grid, block, 0, stream>>>(x, wq, scales, bias, Xb, Wb,
                                                                 out, (int)M, (int)N, (int)K);
        else
            gemm_kernel<false, false><<<grid, block, 0, stream>>>(x, wq, scales, bias, Xb, Wb,
                                                                  out, (int)M, (int)N, (int)K);
    }
}